// Round 1
// 1074.120 us; speedup vs baseline: 1.0854x; 1.0854x over previous
//
#include <hip/hip_runtime.h>
#include <math.h>

#define B_ 16
#define C_ 16
#define P_ 512
#define D_ 256

constexpr int HEADS = B_ * C_;     // 256
constexpr int PD    = P_ * D_;
constexpr float QSCALE = 0.0625f;  // D^-0.5

typedef __attribute__((ext_vector_type(8))) short short8;   // 8 bf16
typedef __attribute__((ext_vector_type(4))) short short4_t; // 4 bf16
typedef __attribute__((ext_vector_type(4))) float floatx4;  // MFMA acc

#define MFMA_BF16 __builtin_amdgcn_mfma_f32_16x16x32_bf16

// fp32 -> (hi bf16, lo bf16) with x ~= hi + lo (residual ~2^-17 rel)
__device__ inline short2 split_hl(float x) {
    unsigned xb = __float_as_uint(x);
    unsigned hb = (xb + 0x8000u) & 0xFFFF0000u;
    float lf = x - __uint_as_float(hb);
    short2 r;
    r.x = (short)(hb >> 16);
    r.y = (short)((__float_as_uint(lf) + 0x8000u) >> 16);
    return r;
}
__device__ inline unsigned packsplit(float x) {
    short2 s = split_hl(x);
    return (unsigned)(unsigned short)s.x | ((unsigned)(unsigned short)s.y << 16);
}

// ---------------------------------------------------------------------------
// global_load_lds helpers: LDS dest is wave-uniform base + lane*16 (linear);
// per-lane GLOBAL source carries the inverse slot-swizzle (rule 21).
// ---------------------------------------------------------------------------
__device__ inline void gload16(const unsigned* g, unsigned* l) {
    __builtin_amdgcn_global_load_lds(
        (__attribute__((address_space(1))) void*)(g),
        (__attribute__((address_space(3))) void*)(l), 16, 0, 0);
}

// Stage a 128-row x 32-word tile (pair-words) from global rows of stride
// `gstride` words into linear LDS [128][32] with 16B-slot XOR swizzle:
// LDS slot t of row r holds global slot t ^ (r&7).
__device__ inline void stage_sw(const unsigned* __restrict__ g, int gstride,
                                unsigned* lds, int tid) {
    int wv = tid >> 6, lane = tid & 63;
    int rsub = lane >> 3, slot = lane & 7;
#pragma unroll
    for (int it = 0; it < 4; ++it) {
        int r0 = it * 32 + wv * 8;        // wave-uniform
        int row = r0 + rsub;
        const unsigned* src = g + (size_t)row * gstride + ((slot ^ (row & 7)) << 2);
        gload16(src, &lds[r0 * 32]);
    }
}

// unpack 8 packed pair-words (2 x uint4) -> hi short8 + lo short8 via v_perm
__device__ inline void unpack8(const uint4& a, const uint4& b, short8& h, short8& l) {
    union { unsigned u[4]; short8 s; } H, L;
    H.u[0] = __builtin_amdgcn_perm(a.y, a.x, 0x05040100u);
    L.u[0] = __builtin_amdgcn_perm(a.y, a.x, 0x07060302u);
    H.u[1] = __builtin_amdgcn_perm(a.w, a.z, 0x05040100u);
    L.u[1] = __builtin_amdgcn_perm(a.w, a.z, 0x07060302u);
    H.u[2] = __builtin_amdgcn_perm(b.y, b.x, 0x05040100u);
    L.u[2] = __builtin_amdgcn_perm(b.y, b.x, 0x07060302u);
    H.u[3] = __builtin_amdgcn_perm(b.w, b.z, 0x05040100u);
    L.u[3] = __builtin_amdgcn_perm(b.w, b.z, 0x07060302u);
    h = H.s; l = L.s;
}

// frag read from swizzled linear [128][32] tile
__device__ inline void rdfrag_sw(const unsigned* lds, int r, int hi,
                                 short8& h, short8& l) {
    int base = r * 32;
    int x = r & 7;
    const uint4 a = *reinterpret_cast<const uint4*>(&lds[base + ((((hi << 1))     ^ x) << 2)]);
    const uint4 b = *reinterpret_cast<const uint4*>(&lds[base + ((((hi << 1) | 1) ^ x) << 2)]);
    unpack8(a, b, h, l);
}

// frag read from padded [128][36] tile (register-staged A in proj)
__device__ inline void rdfrag_pad(const unsigned* lds, int r, int hi,
                                  short8& h, short8& l) {
    const uint4 a = *reinterpret_cast<const uint4*>(&lds[r * 36 + hi * 8]);
    const uint4 b = *reinterpret_cast<const uint4*>(&lds[r * 36 + hi * 8 + 4]);
    unpack8(a, b, h, l);
}

// ---------------------------------------------------------------------------
// S[b,p,d] = sum_c aw[c,p,d] * query[b,c,p,d]
// ---------------------------------------------------------------------------
__global__ __launch_bounds__(256) void k_sum_acw(const float* __restrict__ query,
                                                 const float* __restrict__ aw,
                                                 float* __restrict__ S) {
    int idx = blockIdx.x * 256 + threadIdx.x;
    int e = idx * 4;
    int d = e % D_;
    int p = (e / D_) % P_;
    int b = e / (D_ * P_);
    const float4* q4 = reinterpret_cast<const float4*>(query);
    const float4* a4 = reinterpret_cast<const float4*>(aw);
    int qbase = (((b * C_) * P_ + p) * D_ + d) >> 2;
    int abase = (p * D_ + d) >> 2;
    float4 acc = {0.f, 0.f, 0.f, 0.f};
#pragma unroll
    for (int c = 0; c < C_; ++c) {
        float4 qv = q4[qbase + c * (PD / 4)];
        float4 av = a4[abase + c * (PD / 4)];
        acc.x += qv.x * av.x;
        acc.y += qv.y * av.y;
        acc.z += qv.z * av.z;
        acc.w += qv.w * av.w;
    }
    reinterpret_cast<float4*>(S)[idx] = acc;
}

// ---------------------------------------------------------------------------
// Pack + transpose weights: W2t[wsel][c][n][k] pair-words from W[c][k][n] fp32
// ---------------------------------------------------------------------------
__global__ __launch_bounds__(256) void k_wpack(const float* __restrict__ Wq,
                                               const float* __restrict__ Wk,
                                               const float* __restrict__ Wv,
                                               unsigned* __restrict__ W2t) {
    __shared__ float tile[64][68];
    int wsel = blockIdx.z / C_;
    int c    = blockIdx.z % C_;
    int k0 = blockIdx.x * 64, n0 = blockIdx.y * 64;
    const float* Wsrc = wsel == 0 ? Wq : (wsel == 1 ? Wk : Wv);
    int tid = threadIdx.x;
#pragma unroll
    for (int it = 0; it < 4; ++it) {
        int idx = tid + it * 256;
        int kr = idx >> 4, nc = (idx & 15) * 4;
        float4 f = *reinterpret_cast<const float4*>(
            &Wsrc[(size_t)(c * D_ + k0 + kr) * D_ + n0 + nc]);
        *reinterpret_cast<float4*>(&tile[kr][nc]) = f;
    }
    __syncthreads();
#pragma unroll
    for (int it = 0; it < 4; ++it) {
        int idx = tid + it * 256;
        int nr = idx >> 4, kc = (idx & 15) * 4;
        uint4 u;
        u.x = packsplit(tile[kc + 0][nr]);
        u.y = packsplit(tile[kc + 1][nr]);
        u.z = packsplit(tile[kc + 2][nr]);
        u.w = packsplit(tile[kc + 3][nr]);
        *reinterpret_cast<uint4*>(
            &W2t[((size_t)(wsel * C_ + c) * D_ + n0 + nr) * D_ + k0 + kc]) = u;
    }
}

// ---------------------------------------------------------------------------
// Fused split-bf16 MFMA projection, 2-phase double-buffered pipeline.
// A (query/ctx) register-staged into padded [128][36] pair-word LDS;
// B (W2t) staged via global_load_lds into swizzled linear [128][32].
// blockIdx.z = lh*3 + oid (0=q,1=k,2=v).
// ---------------------------------------------------------------------------
__global__ __launch_bounds__(256) void k_proj_mfma(
    const float* __restrict__ query, const float* __restrict__ aw,
    const float* __restrict__ S, const unsigned* __restrict__ W2t,
    const float* __restrict__ bq, const float* __restrict__ bk,
    const float* __restrict__ bv,
    unsigned* __restrict__ Q2, unsigned* __restrict__ K2,
    unsigned* __restrict__ V2t, int head0) {
    __shared__ unsigned Aw[2][128 * 36];
    __shared__ unsigned Bw[2][128 * 32];
    int tid = threadIdx.x;
    int lane = tid & 63, wv = tid >> 6;
    int wm = wv >> 1, wn = wv & 1;
    int ln = lane & 15, hi = lane >> 4, quad4 = hi * 4;
    int n0 = blockIdx.x * 128;
    int m0 = blockIdx.y * 128;
    int lh = blockIdx.z / 3, oid = blockIdx.z % 3;
    int hd = head0 + lh;
    int b = hd / C_, c = hd % C_;
    const unsigned* Wt = W2t + (size_t)(oid * C_ + c) * D_ * D_;

    int arow = tid >> 3, ack = (tid & 7) * 4;  // A staging: row = arow + 32*it

    floatx4 acc[4][4] = {};

    // ---- prologue: stage tile 0
    stage_sw(Wt + (size_t)n0 * D_, D_, &Bw[0][0], tid);
#pragma unroll
    for (int it = 0; it < 4; ++it) {
        int row = arow + it * 32;
        float4 qv = *reinterpret_cast<const float4*>(
            &query[(size_t)(hd * P_ + m0 + row) * D_ + ack]);
        float x0, x1, x2, x3;
        if (oid == 0) {
            x0 = qv.x; x1 = qv.y; x2 = qv.z; x3 = qv.w;
        } else {
            float4 sv = *reinterpret_cast<const float4*>(
                &S[(size_t)(b * P_ + m0 + row) * D_ + ack]);
            float4 av = *reinterpret_cast<const float4*>(
                &aw[(size_t)(c * P_ + m0 + row) * D_ + ack]);
            x0 = sv.x - av.x * qv.x; x1 = sv.y - av.y * qv.y;
            x2 = sv.z - av.z * qv.z; x3 = sv.w - av.w * qv.w;
        }
        uint4 u;
        u.x = packsplit(x0); u.y = packsplit(x1);
        u.z = packsplit(x2); u.w = packsplit(x3);
        *reinterpret_cast<uint4*>(&Aw[0][row * 36 + ack]) = u;
    }
    __syncthreads();

    int cur = 0;
    for (int t = 0; t < 8; ++t) {
        int nx = cur ^ 1;
        bool pf = t < 7;
        int kk = (t + 1) * 32;
        // issue next-tile loads FIRST (hidden under this tile's MFMA)
        if (pf) stage_sw(Wt + (size_t)n0 * D_ + kk, D_, &Bw[nx][0], tid);
        float4 qv[4], sv[4], av[4];
        if (pf) {
#pragma unroll
            for (int it = 0; it < 4; ++it) {
                int row = arow + it * 32;
                qv[it] = *reinterpret_cast<const float4*>(
                    &query[(size_t)(hd * P_ + m0 + row) * D_ + kk + ack]);
                if (oid != 0) {
                    sv[it] = *reinterpret_cast<const float4*>(
                        &S[(size_t)(b * P_ + m0 + row) * D_ + kk + ack]);
                    av[it] = *reinterpret_cast<const float4*>(
                        &aw[(size_t)(c * P_ + m0 + row) * D_ + kk + ack]);
                }
            }
        }
        // compute current tile
        short8 ah[4], alo[4], bh[4], blo[4];
#pragma unroll
        for (int i = 0; i < 4; ++i) {
            rdfrag_pad(&Aw[cur][0], wm * 64 + i * 16 + ln, hi, ah[i], alo[i]);
            rdfrag_sw(&Bw[cur][0], wn * 64 + i * 16 + ln, hi, bh[i], blo[i]);
        }
#pragma unroll
        for (int i = 0; i < 4; ++i)
#pragma unroll
            for (int j = 0; j < 4; ++j) {
                acc[i][j] = MFMA_BF16(ah[i], bh[j], acc[i][j], 0, 0, 0);
                acc[i][j] = MFMA_BF16(ah[i], blo[j], acc[i][j], 0, 0, 0);
                acc[i][j] = MFMA_BF16(alo[i], bh[j], acc[i][j], 0, 0, 0);
            }
        // finish A staging for next tile (waits the reg loads, post-MFMA)
        if (pf) {
#pragma unroll
            for (int it = 0; it < 4; ++it) {
                int row = arow + it * 32;
                float x0, x1, x2, x3;
                if (oid == 0) {
                    x0 = qv[it].x; x1 = qv[it].y; x2 = qv[it].z; x3 = qv[it].w;
                } else {
                    x0 = sv[it].x - av[it].x * qv[it].x;
                    x1 = sv[it].y - av[it].y * qv[it].y;
                    x2 = sv[it].z - av[it].z * qv[it].z;
                    x3 = sv[it].w - av[it].w * qv[it].w;
                }
                uint4 u;
                u.x = packsplit(x0); u.y = packsplit(x1);
                u.z = packsplit(x2); u.w = packsplit(x3);
                *reinterpret_cast<uint4*>(&Aw[nx][row * 36 + ack]) = u;
            }
        }
        __syncthreads();   // drains vmcnt (GLOADs landed) + lgkm; tile ready
        cur = nx;
    }

    const float* bias = oid == 0 ? bq : (oid == 1 ? bk : bv);
    float scale = oid == 0 ? QSCALE : 1.0f;
#pragma unroll
    for (int j = 0; j < 4; ++j) {
        int n_g = n0 + wn * 64 + j * 16 + ln;
        float bb = bias[c * D_ + n_g];
#pragma unroll
        for (int i = 0; i < 4; ++i) {
            int p0 = m0 + wm * 64 + i * 16 + quad4;
            if (oid == 2) {
                uint4 u;
                u.x = packsplit(fmaxf(acc[i][j][0] + bb, 0.f));
                u.y = packsplit(fmaxf(acc[i][j][1] + bb, 0.f));
                u.z = packsplit(fmaxf(acc[i][j][2] + bb, 0.f));
                u.w = packsplit(fmaxf(acc[i][j][3] + bb, 0.f));
                *reinterpret_cast<uint4*>(&V2t[(size_t)(lh * D_ + n_g) * P_ + p0]) = u;
            } else {
                unsigned* dst = oid == 0 ? Q2 : K2;
#pragma unroll
                for (int r = 0; r < 4; ++r) {
                    float v = fmaxf(acc[i][j][r] + bb, 0.f) * scale;
                    dst[(size_t)(lh * P_ + p0 + r) * D_ + n_g] = packsplit(v);
                }
            }
        }
    }
}

// ---------------------------------------------------------------------------
// scores = Q @ K^T. Both operands are pair-words in HBM -> pure
// global_load_lds staging, 2-phase double-buffered pipeline. K=256.
// ---------------------------------------------------------------------------
__global__ __launch_bounds__(256) void k_scores_mfma(
    const unsigned* __restrict__ Q2, const unsigned* __restrict__ K2,
    float* __restrict__ Sc) {
    __shared__ unsigned Aw[2][128 * 32];
    __shared__ unsigned Bw[2][128 * 32];
    int tid = threadIdx.x;
    int lane = tid & 63, wv = tid >> 6;
    int wm = wv >> 1, wn = wv & 1;
    int ln = lane & 15, hi = lane >> 4, quad4 = hi * 4;
    int n0 = blockIdx.x * 128;
    int m0 = blockIdx.y * 128;
    int lh = blockIdx.z;
    const unsigned* ga = Q2 + ((size_t)lh * P_ + m0) * D_;
    const unsigned* gb = K2 + ((size_t)lh * P_ + n0) * D_;

    floatx4 acc[4][4] = {};

    stage_sw(ga, D_, &Aw[0][0], tid);
    stage_sw(gb, D_, &Bw[0][0], tid);
    __syncthreads();

    int cur = 0;
    for (int t = 0; t < 8; ++t) {
        int nx = cur ^ 1;
        bool pf = t < 7;
        int kk = (t + 1) * 32;
        if (pf) {
            stage_sw(ga + kk, D_, &Aw[nx][0], tid);
            stage_sw(gb + kk, D_, &Bw[nx][0], tid);
        }
        short8 ah[4], alo[4], bh[4], blo[4];
#pragma unroll
        for (int i = 0; i < 4; ++i) {
            rdfrag_sw(&Aw[cur][0], wm * 64 + i * 16 + ln, hi, ah[i], alo[i]);
            rdfrag_sw(&Bw[cur][0], wn * 64 + i * 16 + ln, hi, bh[i], blo[i]);
        }
#pragma unroll
        for (int i = 0; i < 4; ++i)
#pragma unroll
            for (int j = 0; j < 4; ++j) {
                acc[i][j] = MFMA_BF16(ah[i], bh[j], acc[i][j], 0, 0, 0);
                acc[i][j] = MFMA_BF16(ah[i], blo[j], acc[i][j], 0, 0, 0);
                acc[i][j] = MFMA_BF16(alo[i], bh[j], acc[i][j], 0, 0, 0);
            }
        __syncthreads();
        cur = nx;
    }
#pragma unroll
    for (int j = 0; j < 4; ++j) {
        int n_g = n0 + wn * 64 + j * 16 + ln;
#pragma unroll
        for (int i = 0; i < 4; ++i) {
            int p0 = m0 + wm * 64 + i * 16 + quad4;
#pragma unroll
            for (int r = 0; r < 4; ++r)
                Sc[(size_t)lh * P_ * P_ + (size_t)(p0 + r) * P_ + n_g] = acc[i][j][r];
        }
    }
}

// ---------------------------------------------------------------------------
// Row softmax over 512, in place: fp32 scores -> packed (hi,lo) attn words.
// ---------------------------------------------------------------------------
__global__ __launch_bounds__(256) void k_softmax_pack(float* __restrict__ Sc) {
    __shared__ float red[4];
    size_t row = blockIdx.x;
    int tid = threadIdx.x;
    float* r = Sc + row * P_;
    float v0 = r[tid], v1 = r[tid + 256];
    int lane = tid & 63, wid = tid >> 6;

    float m = fmaxf(v0, v1);
#pragma unroll
    for (int off = 32; off; off >>= 1) m = fmaxf(m, __shfl_xor(m, off));
    if (lane == 0) red[wid] = m;
    __syncthreads();
    m = fmaxf(fmaxf(red[0], red[1]), fmaxf(red[2], red[3]));
    __syncthreads();

    float e0 = __expf(v0 - m), e1 = __expf(v1 - m);
    float s = e0 + e1;
#pragma unroll
    for (int off = 32; off; off >>= 1) s += __shfl_xor(s, off);
    if (lane == 0) red[wid] = s;
    __syncthreads();
    s = red[0] + red[1] + red[2] + red[3];
    float inv = 1.0f / s;
    unsigned* w = reinterpret_cast<unsigned*>(r);
    w[tid] = packsplit(e0 * inv);
    w[tid + 256] = packsplit(e1 * inv);
}

// ---------------------------------------------------------------------------
// out = attn @ V. A = attn pairs [p][q], B = V2t pairs [e][q]. K=512.
// Pure global_load_lds staging, 2-phase double-buffered pipeline.
// ---------------------------------------------------------------------------
__global__ __launch_bounds__(256) void k_out_mfma(
    const unsigned* __restrict__ A2, const unsigned* __restrict__ V2t,
    float* __restrict__ O, int head0) {
    __shared__ unsigned Aw[2][128 * 32];
    __shared__ unsigned Bw[2][128 * 32];
    int tid = threadIdx.x;
    int lane = tid & 63, wv = tid >> 6;
    int wm = wv >> 1, wn = wv & 1;
    int ln = lane & 15, hi = lane >> 4, quad4 = hi * 4;
    int n0 = blockIdx.x * 128;
    int m0 = blockIdx.y * 128;
    int lh = blockIdx.z;
    int hd = head0 + lh;
    const unsigned* ga = A2 + (size_t)lh * P_ * P_ + (size_t)m0 * P_;
    const unsigned* gb = V2t + ((size_t)lh * D_ + n0) * P_;

    floatx4 acc[4][4] = {};

    stage_sw(ga, P_, &Aw[0][0], tid);
    stage_sw(gb, P_, &Bw[0][0], tid);
    __syncthreads();

    int cur = 0;
    for (int t = 0; t < 16; ++t) {
        int nx = cur ^ 1;
        bool pf = t < 15;
        int kk = (t + 1) * 32;
        if (pf) {
            stage_sw(ga + kk, P_, &Aw[nx][0], tid);
            stage_sw(gb + kk, P_, &Bw[nx][0], tid);
        }
        short8 ah[4], alo[4], bh[4], blo[4];
#pragma unroll
        for (int i = 0; i < 4; ++i) {
            rdfrag_sw(&Aw[cur][0], wm * 64 + i * 16 + ln, hi, ah[i], alo[i]);
            rdfrag_sw(&Bw[cur][0], wn * 64 + i * 16 + ln, hi, bh[i], blo[i]);
        }
#pragma unroll
        for (int i = 0; i < 4; ++i)
#pragma unroll
            for (int j = 0; j < 4; ++j) {
                acc[i][j] = MFMA_BF16(ah[i], bh[j], acc[i][j], 0, 0, 0);
                acc[i][j] = MFMA_BF16(ah[i], blo[j], acc[i][j], 0, 0, 0);
                acc[i][j] = MFMA_BF16(alo[i], bh[j], acc[i][j], 0, 0, 0);
            }
        __syncthreads();
        cur = nx;
    }
#pragma unroll
    for (int j = 0; j < 4; ++j) {
        int n_g = n0 + wn * 64 + j * 16 + ln;
#pragma unroll
        for (int i = 0; i < 4; ++i) {
            int p0 = m0 + wm * 64 + i * 16 + quad4;
#pragma unroll
            for (int r = 0; r < 4; ++r)
                O[(size_t)(hd * P_ + p0 + r) * D_ + n_g] = acc[i][j][r];
        }
    }
}

// ---------------------------------------------------------------------------
extern "C" void kernel_launch(void* const* d_in, const int* in_sizes, int n_in,
                              void* d_out, int out_size, void* d_ws, size_t ws_size,
                              hipStream_t stream) {
    (void)in_sizes; (void)n_in; (void)out_size;
    const float* query = (const float*)d_in[0];
    const float* aw    = (const float*)d_in[1];
    const float* Wq    = (const float*)d_in[2];
    const float* Wk    = (const float*)d_in[3];
    const float* Wv    = (const float*)d_in[4];
    const float* bq    = (const float*)d_in[5];
    const float* bk    = (const float*)d_in[6];
    const float* bv    = (const float*)d_in[7];
    float* out = (float*)d_out;

    char* ws = (char*)d_ws;
    const size_t s_words   = (size_t)B_ * P_ * D_;
    const size_t w2t_words = (size_t)3 * C_ * D_ * D_;
    const size_t fixed_bytes = (s_words + w2t_words) * 4;
    const size_t per_head_bytes = ((size_t)3 * P_ * D_ + (size_t)P_ * P_) * 4;
    size_t avail = ws_size > fixed_bytes ? ws_size - fixed_bytes : 0;
    int H = (int)(avail / per_head_bytes);
    if (H < 1) H = 1;
    if (H > HEADS) H = HEADS;

    float*    S   = (float*)ws;
    unsigned* W2t = (unsigned*)(ws + s_words * 4);
    unsigned* Q2  = (unsigned*)(ws + fixed_bytes);
    unsigned* K2  = Q2 + (size_t)H * P_ * D_;
    unsigned* V2t = K2 + (size_t)H * P_ * D_;
    float*    Sc  = (float*)(V2t + (size_t)H * P_ * D_);

    k_sum_acw<<<(B_ * P_ * D_ / 4) / 256, 256, 0, stream>>>(query, aw, S);
    k_wpack<<<dim3(D_ / 64, D_ / 64, 3 * C_), 256, 0, stream>>>(Wq, Wk, Wv, W2t);

    for (int head0 = 0; head0 < HEADS; head0 += H) {
        int Hc = HEADS - head0 < H ? HEADS - head0 : H;
        k_proj_mfma<<<dim3(D_ / 128, P_ / 128, 3 * Hc), 256, 0, stream>>>(
            query, aw, S, W2t, bq, bk, bv, Q2, K2, V2t, head0);
        k_scores_mfma<<<dim3(P_ / 128, P_ / 128, Hc), 256, 0, stream>>>(Q2, K2, Sc);
        k_softmax_pack<<<Hc * P_, 256, 0, stream>>>(Sc);
        k_out_mfma<<<dim3(D_ / 128, P_ / 128, Hc), 256, 0, stream>>>(
            (const unsigned*)Sc, V2t, out, head0);
    }
}

// Round 3
// 919.139 us; speedup vs baseline: 1.2684x; 1.1686x over previous
//
#include <hip/hip_runtime.h>
#include <math.h>

#define B_ 16
#define C_ 16
#define P_ 512
#define D_ 256

constexpr int HEADS = B_ * C_;     // 256
constexpr int PD    = P_ * D_;
constexpr float QSCALE = 0.0625f;  // D^-0.5

typedef __attribute__((ext_vector_type(8))) short short8;   // 8 bf16
typedef __attribute__((ext_vector_type(4))) short short4_t; // 4 bf16
typedef __attribute__((ext_vector_type(4))) float floatx4;  // MFMA acc

#define MFMA_BF16 __builtin_amdgcn_mfma_f32_16x16x32_bf16

// fp32 -> (hi bf16, lo bf16) with x ~= hi + lo (residual ~2^-17 rel)
__device__ inline short2 split_hl(float x) {
    unsigned xb = __float_as_uint(x);
    unsigned hb = (xb + 0x8000u) & 0xFFFF0000u;
    float lf = x - __uint_as_float(hb);
    short2 r;
    r.x = (short)(hb >> 16);
    r.y = (short)((__float_as_uint(lf) + 0x8000u) >> 16);
    return r;
}
__device__ inline unsigned packsplit(float x) {
    short2 s = split_hl(x);
    return (unsigned)(unsigned short)s.x | ((unsigned)(unsigned short)s.y << 16);
}

// ---------------------------------------------------------------------------
// global_load_lds: LDS dest is wave-uniform base + lane*16 (linear);
// per-lane GLOBAL source carries the inverse slot-swizzle (rule 21).
// ---------------------------------------------------------------------------
__device__ inline void gload16(const unsigned* g, unsigned* l) {
    __builtin_amdgcn_global_load_lds(
        (__attribute__((address_space(1))) void*)(g),
        (__attribute__((address_space(3))) void*)(l), 16, 0, 0);
}

// Stage a 128-row x 32-word tile from global rows of stride gstride words
// into linear LDS [128][32] with 16B-slot XOR swizzle (4-wave blocks).
__device__ inline void stage_sw(const unsigned* __restrict__ g, int gstride,
                                unsigned* lds, int tid) {
    int wv = tid >> 6, lane = tid & 63;
    int rsub = lane >> 3, slot = lane & 7;
#pragma unroll
    for (int it = 0; it < 4; ++it) {
        int r0 = it * 32 + wv * 8;        // wave-uniform
        int row = r0 + rsub;
        const unsigned* src = g + (size_t)row * gstride + ((slot ^ (row & 7)) << 2);
        gload16(src, &lds[r0 * 32]);
    }
}

// 8-wave (512-thread) version of the same.
__device__ inline void stage_sw8(const unsigned* __restrict__ g, int gstride,
                                 unsigned* lds, int tid) {
    int wv = tid >> 6, lane = tid & 63;
    int rsub = lane >> 3, slot = lane & 7;
#pragma unroll
    for (int it = 0; it < 2; ++it) {
        int r0 = it * 64 + wv * 8;        // wave-uniform
        int row = r0 + rsub;
        const unsigned* src = g + (size_t)row * gstride + ((slot ^ (row & 7)) << 2);
        gload16(src, &lds[r0 * 32]);
    }
}

// unpack 8 packed pair-words (2 x uint4) -> hi short8 + lo short8 via v_perm
__device__ inline void unpack8(const uint4& a, const uint4& b, short8& h, short8& l) {
    union { unsigned u[4]; short8 s; } H, L;
    H.u[0] = __builtin_amdgcn_perm(a.y, a.x, 0x05040100u);
    L.u[0] = __builtin_amdgcn_perm(a.y, a.x, 0x07060302u);
    H.u[1] = __builtin_amdgcn_perm(a.w, a.z, 0x05040100u);
    L.u[1] = __builtin_amdgcn_perm(a.w, a.z, 0x07060302u);
    H.u[2] = __builtin_amdgcn_perm(b.y, b.x, 0x05040100u);
    L.u[2] = __builtin_amdgcn_perm(b.y, b.x, 0x07060302u);
    H.u[3] = __builtin_amdgcn_perm(b.w, b.z, 0x05040100u);
    L.u[3] = __builtin_amdgcn_perm(b.w, b.z, 0x07060302u);
    h = H.s; l = L.s;
}

// frag read from swizzled linear [rows][32] tile
__device__ inline void rdfrag_sw(const unsigned* lds, int r, int hi,
                                 short8& h, short8& l) {
    int base = r * 32;
    int x = r & 7;
    const uint4 a = *reinterpret_cast<const uint4*>(&lds[base + ((((hi << 1))     ^ x) << 2)]);
    const uint4 b = *reinterpret_cast<const uint4*>(&lds[base + ((((hi << 1) | 1) ^ x) << 2)]);
    unpack8(a, b, h, l);
}

// frag read from padded [128][36] tile (register-staged A in proj)
__device__ inline void rdfrag_pad(const unsigned* lds, int r, int hi,
                                  short8& h, short8& l) {
    const uint4 a = *reinterpret_cast<const uint4*>(&lds[r * 36 + hi * 8]);
    const uint4 b = *reinterpret_cast<const uint4*>(&lds[r * 36 + hi * 8 + 4]);
    unpack8(a, b, h, l);
}

// ---------------------------------------------------------------------------
// S[b,p,d] = sum_c aw[c,p,d] * query[b,c,p,d]
// ---------------------------------------------------------------------------
__global__ __launch_bounds__(256) void k_sum_acw(const float* __restrict__ query,
                                                 const float* __restrict__ aw,
                                                 float* __restrict__ S) {
    int idx = blockIdx.x * 256 + threadIdx.x;
    int e = idx * 4;
    int d = e % D_;
    int p = (e / D_) % P_;
    int b = e / (D_ * P_);
    const float4* q4 = reinterpret_cast<const float4*>(query);
    const float4* a4 = reinterpret_cast<const float4*>(aw);
    int qbase = (((b * C_) * P_ + p) * D_ + d) >> 2;
    int abase = (p * D_ + d) >> 2;
    float4 acc = {0.f, 0.f, 0.f, 0.f};
#pragma unroll
    for (int c = 0; c < C_; ++c) {
        float4 qv = q4[qbase + c * (PD / 4)];
        float4 av = a4[abase + c * (PD / 4)];
        acc.x += qv.x * av.x;
        acc.y += qv.y * av.y;
        acc.z += qv.z * av.z;
        acc.w += qv.w * av.w;
    }
    reinterpret_cast<float4*>(S)[idx] = acc;
}

// ---------------------------------------------------------------------------
// Pack + transpose weights: W2t[wsel][c][n][k] pair-words from W[c][k][n] fp32
// ---------------------------------------------------------------------------
__global__ __launch_bounds__(256) void k_wpack(const float* __restrict__ Wq,
                                               const float* __restrict__ Wk,
                                               const float* __restrict__ Wv,
                                               unsigned* __restrict__ W2t) {
    __shared__ float tile[64][68];
    int wsel = blockIdx.z / C_;
    int c    = blockIdx.z % C_;
    int k0 = blockIdx.x * 64, n0 = blockIdx.y * 64;
    const float* Wsrc = wsel == 0 ? Wq : (wsel == 1 ? Wk : Wv);
    int tid = threadIdx.x;
#pragma unroll
    for (int it = 0; it < 4; ++it) {
        int idx = tid + it * 256;
        int kr = idx >> 4, nc = (idx & 15) * 4;
        float4 f = *reinterpret_cast<const float4*>(
            &Wsrc[(size_t)(c * D_ + k0 + kr) * D_ + n0 + nc]);
        *reinterpret_cast<float4*>(&tile[kr][nc]) = f;
    }
    __syncthreads();
#pragma unroll
    for (int it = 0; it < 4; ++it) {
        int idx = tid + it * 256;
        int nr = idx >> 4, kc = (idx & 15) * 4;
        uint4 u;
        u.x = packsplit(tile[kc + 0][nr]);
        u.y = packsplit(tile[kc + 1][nr]);
        u.z = packsplit(tile[kc + 2][nr]);
        u.w = packsplit(tile[kc + 3][nr]);
        *reinterpret_cast<uint4*>(
            &W2t[((size_t)(wsel * C_ + c) * D_ + n0 + nr) * D_ + k0 + kc]) = u;
    }
}

// ---------------------------------------------------------------------------
// Fused split-bf16 MFMA projection, 2-phase double-buffered pipeline.
// ---------------------------------------------------------------------------
__global__ __launch_bounds__(256) void k_proj_mfma(
    const float* __restrict__ query, const float* __restrict__ aw,
    const float* __restrict__ S, const unsigned* __restrict__ W2t,
    const float* __restrict__ bq, const float* __restrict__ bk,
    const float* __restrict__ bv,
    unsigned* __restrict__ Q2, unsigned* __restrict__ K2,
    unsigned* __restrict__ V2t, int head0) {
    __shared__ unsigned Aw[2][128 * 36];
    __shared__ unsigned Bw[2][128 * 32];
    int tid = threadIdx.x;
    int lane = tid & 63, wv = tid >> 6;
    int wm = wv >> 1, wn = wv & 1;
    int ln = lane & 15, hi = lane >> 4, quad4 = hi * 4;
    int n0 = blockIdx.x * 128;
    int m0 = blockIdx.y * 128;
    int lh = blockIdx.z / 3, oid = blockIdx.z % 3;
    int hd = head0 + lh;
    int b = hd / C_, c = hd % C_;
    const unsigned* Wt = W2t + (size_t)(oid * C_ + c) * D_ * D_;

    int arow = tid >> 3, ack = (tid & 7) * 4;

    floatx4 acc[4][4] = {};

    stage_sw(Wt + (size_t)n0 * D_, D_, &Bw[0][0], tid);
#pragma unroll
    for (int it = 0; it < 4; ++it) {
        int row = arow + it * 32;
        float4 qv = *reinterpret_cast<const float4*>(
            &query[(size_t)(hd * P_ + m0 + row) * D_ + ack]);
        float x0, x1, x2, x3;
        if (oid == 0) {
            x0 = qv.x; x1 = qv.y; x2 = qv.z; x3 = qv.w;
        } else {
            float4 sv = *reinterpret_cast<const float4*>(
                &S[(size_t)(b * P_ + m0 + row) * D_ + ack]);
            float4 av = *reinterpret_cast<const float4*>(
                &aw[(size_t)(c * P_ + m0 + row) * D_ + ack]);
            x0 = sv.x - av.x * qv.x; x1 = sv.y - av.y * qv.y;
            x2 = sv.z - av.z * qv.z; x3 = sv.w - av.w * qv.w;
        }
        uint4 u;
        u.x = packsplit(x0); u.y = packsplit(x1);
        u.z = packsplit(x2); u.w = packsplit(x3);
        *reinterpret_cast<uint4*>(&Aw[0][row * 36 + ack]) = u;
    }
    __syncthreads();

    int cur = 0;
    for (int t = 0; t < 8; ++t) {
        int nx = cur ^ 1;
        bool pf = t < 7;
        int kk = (t + 1) * 32;
        if (pf) stage_sw(Wt + (size_t)n0 * D_ + kk, D_, &Bw[nx][0], tid);
        float4 qv[4], sv[4], av[4];
        if (pf) {
#pragma unroll
            for (int it = 0; it < 4; ++it) {
                int row = arow + it * 32;
                qv[it] = *reinterpret_cast<const float4*>(
                    &query[(size_t)(hd * P_ + m0 + row) * D_ + kk + ack]);
                if (oid != 0) {
                    sv[it] = *reinterpret_cast<const float4*>(
                        &S[(size_t)(b * P_ + m0 + row) * D_ + kk + ack]);
                    av[it] = *reinterpret_cast<const float4*>(
                        &aw[(size_t)(c * P_ + m0 + row) * D_ + kk + ack]);
                }
            }
        }
        short8 ah[4], alo[4], bh[4], blo[4];
#pragma unroll
        for (int i = 0; i < 4; ++i) {
            rdfrag_pad(&Aw[cur][0], wm * 64 + i * 16 + ln, hi, ah[i], alo[i]);
            rdfrag_sw(&Bw[cur][0], wn * 64 + i * 16 + ln, hi, bh[i], blo[i]);
        }
#pragma unroll
        for (int i = 0; i < 4; ++i)
#pragma unroll
            for (int j = 0; j < 4; ++j) {
                acc[i][j] = MFMA_BF16(ah[i], bh[j], acc[i][j], 0, 0, 0);
                acc[i][j] = MFMA_BF16(ah[i], blo[j], acc[i][j], 0, 0, 0);
                acc[i][j] = MFMA_BF16(alo[i], bh[j], acc[i][j], 0, 0, 0);
            }
        if (pf) {
#pragma unroll
            for (int it = 0; it < 4; ++it) {
                int row = arow + it * 32;
                float x0, x1, x2, x3;
                if (oid == 0) {
                    x0 = qv[it].x; x1 = qv[it].y; x2 = qv[it].z; x3 = qv[it].w;
                } else {
                    x0 = sv[it].x - av[it].x * qv[it].x;
                    x1 = sv[it].y - av[it].y * qv[it].y;
                    x2 = sv[it].z - av[it].z * qv[it].z;
                    x3 = sv[it].w - av[it].w * qv[it].w;
                }
                uint4 u;
                u.x = packsplit(x0); u.y = packsplit(x1);
                u.z = packsplit(x2); u.w = packsplit(x3);
                *reinterpret_cast<uint4*>(&Aw[nx][row * 36 + ack]) = u;
            }
        }
        __syncthreads();
        cur = nx;
    }

    const float* bias = oid == 0 ? bq : (oid == 1 ? bk : bv);
    float scale = oid == 0 ? QSCALE : 1.0f;
#pragma unroll
    for (int j = 0; j < 4; ++j) {
        int n_g = n0 + wn * 64 + j * 16 + ln;
        float bb = bias[c * D_ + n_g];
#pragma unroll
        for (int i = 0; i < 4; ++i) {
            int p0 = m0 + wm * 64 + i * 16 + quad4;
            if (oid == 2) {
                uint4 u;
                u.x = packsplit(fmaxf(acc[i][j][0] + bb, 0.f));
                u.y = packsplit(fmaxf(acc[i][j][1] + bb, 0.f));
                u.z = packsplit(fmaxf(acc[i][j][2] + bb, 0.f));
                u.w = packsplit(fmaxf(acc[i][j][3] + bb, 0.f));
                *reinterpret_cast<uint4*>(&V2t[(size_t)(lh * D_ + n_g) * P_ + p0]) = u;
            } else {
                unsigned* dst = oid == 0 ? Q2 : K2;
#pragma unroll
                for (int r = 0; r < 4; ++r) {
                    float v = fmaxf(acc[i][j][r] + bb, 0.f) * scale;
                    dst[(size_t)(lh * P_ + p0 + r) * D_ + n_g] = packsplit(v);
                }
            }
        }
    }
}

// ---------------------------------------------------------------------------
// Fused flash attention: scores + softmax + PV in one kernel.
// Block = 512 threads (8 waves), one head x 128 Q-rows. Each wave owns 16
// Q-rows and the full D=256 output. 4 KV-tiles of 128, online softmax.
// LDS: 4 x 16KB chunk pool (QK db / V db time-shared) + 8 x 8KB per-wave
// P-transpose buffers (wave-private; same XOR involution on write & read).
// ---------------------------------------------------------------------------
__global__ __launch_bounds__(512) void k_attn(
    const unsigned* __restrict__ Q2, const unsigned* __restrict__ K2,
    const unsigned* __restrict__ V2t, float* __restrict__ O, int head0) {
    __shared__ unsigned chunk[4][128 * 32];  // 64 KB staging pool
    __shared__ unsigned Pl[8][16 * 128];     // 64 KB per-wave P (private)
    int tid = threadIdx.x;
    int lane = tid & 63, wv = tid >> 6;
    int ln = lane & 15, hi = lane >> 4;
    int lh = blockIdx.x;              // head-major: a head's 4 blocks share XCD
    int m0 = blockIdx.y * 128;
    int hd = head0 + lh;
    const unsigned* gq = Q2 + ((size_t)lh * P_ + m0) * D_;
    const unsigned* gk = K2 + (size_t)lh * P_ * D_;
    const unsigned* gv = V2t + (size_t)lh * D_ * P_;
    unsigned* myP = &Pl[wv][0];

    floatx4 o[16] = {};
    float m_[4], l_[4];
#pragma unroll
    for (int r = 0; r < 4; ++r) { m_[r] = -INFINITY; l_[r] = 0.f; }

    // prologue: QK tile kk=0 of kv=0
    stage_sw8(gq, D_, chunk[0], tid);
    stage_sw8(gk, D_, chunk[2], tid);
    __syncthreads();
    int cur = 0;

    for (int kv = 0; kv < 4; ++kv) {
        // ---- QK^T phase: S-tile 16 rows x 128 cols per wave
        floatx4 s_[8] = {};
        for (int kk = 0; kk < 8; ++kk) {
            int nx = cur ^ 1;
            if (kk < 7) {
                stage_sw8(gq + (kk + 1) * 32, D_, chunk[nx], tid);
                stage_sw8(gk + (size_t)(kv * 128) * D_ + (kk + 1) * 32, D_,
                          chunk[2 + nx], tid);
            } else {
                // prefetch V tile kq=0 into the free half
                stage_sw8(gv + kv * 128, P_, chunk[nx], tid);
                stage_sw8(gv + (size_t)128 * P_ + kv * 128, P_, chunk[2 + nx], tid);
            }
            short8 ah, al_, bh, bl_;
            rdfrag_sw(chunk[cur], wv * 16 + ln, hi, ah, al_);
            __builtin_amdgcn_s_setprio(1);
#pragma unroll
            for (int j = 0; j < 8; ++j) {
                rdfrag_sw(chunk[2 + cur], j * 16 + ln, hi, bh, bl_);
                s_[j] = MFMA_BF16(ah, bh, s_[j], 0, 0, 0);
                s_[j] = MFMA_BF16(ah, bl_, s_[j], 0, 0, 0);
                s_[j] = MFMA_BF16(al_, bh, s_[j], 0, 0, 0);
            }
            __builtin_amdgcn_s_setprio(0);
            __syncthreads();
            cur = nx;
        }

        // ---- online softmax (register + 16-lane shuffles; no barrier)
        float sc[4], rs[4];
#pragma unroll
        for (int r = 0; r < 4; ++r) {
            float mx = s_[0][r];
#pragma unroll
            for (int j = 1; j < 8; ++j) mx = fmaxf(mx, s_[j][r]);
            mx = fmaxf(mx, __shfl_xor(mx, 1));
            mx = fmaxf(mx, __shfl_xor(mx, 2));
            mx = fmaxf(mx, __shfl_xor(mx, 4));
            mx = fmaxf(mx, __shfl_xor(mx, 8));
            float mn = fmaxf(m_[r], mx);
            sc[r] = __expf(m_[r] - mn);
            m_[r] = mn;
            rs[r] = 0.f;
        }
#pragma unroll
        for (int n = 0; n < 16; ++n)
#pragma unroll
            for (int r = 0; r < 4; ++r) o[n][r] *= sc[r];

        // P = exp(s - m), pack hi/lo, transpose-write to private LDS
#pragma unroll
        for (int j = 0; j < 8; ++j)
#pragma unroll
            for (int r = 0; r < 4; ++r) {
                float p = __expf(s_[j][r] - m_[r]);
                rs[r] += p;
                int row = hi * 4 + r, col = j * 16 + ln;
                int slot = (col >> 2) ^ (row & 7);
                myP[row * 128 + slot * 4 + (col & 3)] = packsplit(p);
            }
#pragma unroll
        for (int r = 0; r < 4; ++r) {
            float s = rs[r];
            s += __shfl_xor(s, 1);
            s += __shfl_xor(s, 2);
            s += __shfl_xor(s, 4);
            s += __shfl_xor(s, 8);
            l_[r] = l_[r] * sc[r] + s;
        }

        // ---- PV phase: 4 k-steps of 32 over this KV tile
        for (int kq = 0; kq < 4; ++kq) {
            int nx = cur ^ 1;
            if (kq < 3) {
                stage_sw8(gv + kv * 128 + (kq + 1) * 32, P_, chunk[nx], tid);
                stage_sw8(gv + (size_t)128 * P_ + kv * 128 + (kq + 1) * 32, P_,
                          chunk[2 + nx], tid);
            } else if (kv < 3) {
                stage_sw8(gq, D_, chunk[nx], tid);
                stage_sw8(gk + (size_t)((kv + 1) * 128) * D_, D_, chunk[2 + nx], tid);
            }
            // A-frag: P rows = ln, k-slots = kq*8 + 2*hi (+swizzle key ln&7)
            int x = ln & 7;
            const uint4 a0 = *reinterpret_cast<const uint4*>(
                &myP[ln * 128 + (((kq * 8 + 2 * hi)) ^ x) * 4]);
            const uint4 a1 = *reinterpret_cast<const uint4*>(
                &myP[ln * 128 + (((kq * 8 + 2 * hi + 1)) ^ x) * 4]);
            short8 pah, pal;
            unpack8(a0, a1, pah, pal);
            __builtin_amdgcn_s_setprio(1);
#pragma unroll
            for (int n = 0; n < 16; ++n) {
                short8 vh, vl;
                const unsigned* vb = (n < 8) ? chunk[cur] : chunk[2 + cur];
                rdfrag_sw(vb, (n & 7) * 16 + ln, hi, vh, vl);
                o[n] = MFMA_BF16(pah, vh, o[n], 0, 0, 0);
                o[n] = MFMA_BF16(pah, vl, o[n], 0, 0, 0);
                o[n] = MFMA_BF16(pal, vh, o[n], 0, 0, 0);
            }
            __builtin_amdgcn_s_setprio(0);
            __syncthreads();
            cur = nx;
        }
    }

    // ---- epilogue: divide by row sum, write fp32
    float inv[4];
#pragma unroll
    for (int r = 0; r < 4; ++r) inv[r] = 1.0f / l_[r];
#pragma unroll
    for (int n = 0; n < 16; ++n) {
        int col = n * 16 + ln;
#pragma unroll
        for (int r = 0; r < 4; ++r) {
            int row = m0 + wv * 16 + hi * 4 + r;
            O[((size_t)hd * P_ + row) * D_ + col] = o[n][r] * inv[r];
        }
    }
}

// ---------------------------------------------------------------------------
extern "C" void kernel_launch(void* const* d_in, const int* in_sizes, int n_in,
                              void* d_out, int out_size, void* d_ws, size_t ws_size,
                              hipStream_t stream) {
    (void)in_sizes; (void)n_in; (void)out_size;
    const float* query = (const float*)d_in[0];
    const float* aw    = (const float*)d_in[1];
    const float* Wq    = (const float*)d_in[2];
    const float* Wk    = (const float*)d_in[3];
    const float* Wv    = (const float*)d_in[4];
    const float* bq    = (const float*)d_in[5];
    const float* bk    = (const float*)d_in[6];
    const float* bv    = (const float*)d_in[7];
    float* out = (float*)d_out;

    char* ws = (char*)d_ws;
    const size_t s_words   = (size_t)B_ * P_ * D_;
    const size_t w2t_words = (size_t)3 * C_ * D_ * D_;
    const size_t fixed_bytes = (s_words + w2t_words) * 4;
    const size_t per_head_bytes = (size_t)3 * P_ * D_ * 4;  // Q2,K2,V2t (no Sc)
    size_t avail = ws_size > fixed_bytes ? ws_size - fixed_bytes : 0;
    int H = (int)(avail / per_head_bytes);
    if (H < 1) H = 1;
    if (H > HEADS) H = HEADS;

    float*    S   = (float*)ws;
    unsigned* W2t = (unsigned*)(ws + s_words * 4);
    unsigned* Q2  = (unsigned*)(ws + fixed_bytes);
    unsigned* K2  = Q2 + (size_t)H * P_ * D_;
    unsigned* V2t = K2 + (size_t)H * P_ * D_;

    k_sum_acw<<<(B_ * P_ * D_ / 4) / 256, 256, 0, stream>>>(query, aw, S);
    k_wpack<<<dim3(D_ / 64, D_ / 64, 3 * C_), 256, 0, stream>>>(Wq, Wk, Wv, W2t);

    for (int head0 = 0; head0 < HEADS; head0 += H) {
        int Hc = HEADS - head0 < H ? HEADS - head0 : H;
        k_proj_mfma<<<dim3(D_ / 128, P_ / 128, 3 * Hc), 256, 0, stream>>>(
            query, aw, S, W2t, bq, bk, bv, Q2, K2, V2t, head0);
        k_attn<<<dim3(Hc, P_ / 128), 512, 0, stream>>>(Q2, K2, V2t, out, head0);
    }
}